// Round 9
// baseline (917.054 us; speedup 1.0000x reference)
//
#include <hip/hip_runtime.h>
#include <math.h>

// DecoderBlock: B=8, T=1024, D=768, H=12, HD=64
// x fp32 [B,T,D]; per-head wq/wk/wv [H,D,HD]; w_proj [D,D]; w_fc [D,4D]; w_cp [4D,D]
// out fp32 [B,T,D]
//
// NOTE 1: global_load_lds (direct-to-LDS) produced stale reads on warm launches
// when the source was written by a preceding kernel (R3). VGPR staging only.
// NOTE 2: without an explicit min-waves launch bound, the compiler capped the
// pipelined GEMM at 60 VGPRs and spilled the prefetch registers to scratch
// (R7: WRITE_SIZE 689 MB vs 25 MB output, 27x). __launch_bounds__(256, MINW)
// pins the register budget so the prefetch stays in VGPRs.

typedef unsigned short ushort_t;
typedef __attribute__((ext_vector_type(8))) __bf16 bf16x8;
typedef __attribute__((ext_vector_type(4))) __bf16 bf16x4;
typedef __attribute__((ext_vector_type(4))) float floatx4;

__device__ __forceinline__ float bf2f(ushort_t u) {
  unsigned int x = ((unsigned int)u) << 16;
  return __builtin_bit_cast(float, x);
}
__device__ __forceinline__ ushort_t f2bf(float f) {
  unsigned int x = __builtin_bit_cast(unsigned int, f);
  unsigned int r = (x + 0x7FFFu + ((x >> 16) & 1u)) >> 16;
  return (ushort_t)r;
}

// ---------------- weight repack: fp32 [R][C] -> bf16 [C][R] (tiled, coalesced) ----------
__global__ void __launch_bounds__(256) transpose_w(const float* __restrict__ in,
                                                   ushort_t* __restrict__ out,
                                                   int R, int C) {
  __shared__ ushort_t tl[64][65];
  int c0 = blockIdx.x * 64, r0 = blockIdx.y * 64;
  #pragma unroll
  for (int i = 0; i < 16; ++i) {
    int idx = threadIdx.x + i * 256;
    int r = idx >> 6, c = idx & 63;
    tl[c][r] = f2bf(in[(size_t)(r0 + r) * C + c0 + c]);
  }
  __syncthreads();
  #pragma unroll
  for (int i = 0; i < 16; ++i) {
    int idx = threadIdx.x + i * 256;
    int c = idx >> 6, r = idx & 63;
    out[(size_t)(c0 + c) * R + r0 + r] = tl[c][r];
  }
}

// wq/wk/wv [H,D,HD] fp32 -> wqkvT [N=2304][K=768] bf16 (N = s*768 + h*64 + hd)
__global__ void __launch_bounds__(256) repack_qkv_t(const float* __restrict__ wq,
                                                    const float* __restrict__ wk,
                                                    const float* __restrict__ wv,
                                                    ushort_t* __restrict__ out) {
  __shared__ ushort_t tl[64][65];
  int s = blockIdx.y / 12, h = blockIdx.y % 12;
  const float* w = ((s == 0) ? wq : (s == 1) ? wk : wv) + (size_t)h * 768 * 64;
  int d0 = blockIdx.x * 64;
  #pragma unroll
  for (int i = 0; i < 16; ++i) {
    int idx = threadIdx.x + i * 256;
    int r = idx >> 6, c = idx & 63;   // r: d offset, c: hd
    tl[c][r] = f2bf(w[(size_t)(d0 + r) * 64 + c]);
  }
  __syncthreads();
  ushort_t* ob = out + (size_t)(s * 768 + h * 64) * 768;
  #pragma unroll
  for (int i = 0; i < 16; ++i) {
    int idx = threadIdx.x + i * 256;
    int c = idx >> 6, r = idx & 63;   // c: hd, r: d offset
    ob[(size_t)c * 768 + d0 + r] = tl[c][r];
  }
}

// ---------------- layernorm: fp32 row [768] -> bf16 row ----------------
__global__ void __launch_bounds__(256) ln_kernel(const float* __restrict__ x,
                                                 const float* __restrict__ g,
                                                 const float* __restrict__ b,
                                                 ushort_t* __restrict__ out) {
  int row = blockIdx.x;
  int tid = threadIdx.x;
  const float* xr = x + (size_t)row * 768;
  float v0 = xr[tid], v1 = xr[tid + 256], v2 = xr[tid + 512];
  float s = v0 + v1 + v2;
  float s2 = v0 * v0 + v1 * v1 + v2 * v2;
  #pragma unroll
  for (int off = 32; off; off >>= 1) {
    s += __shfl_xor(s, off, 64);
    s2 += __shfl_xor(s2, off, 64);
  }
  __shared__ float ws1[4], ws2[4];
  int w = tid >> 6;
  if ((tid & 63) == 0) { ws1[w] = s; ws2[w] = s2; }
  __syncthreads();
  float S = ws1[0] + ws1[1] + ws1[2] + ws1[3];
  float S2 = ws2[0] + ws2[1] + ws2[2] + ws2[3];
  float mean = S * (1.0f / 768.0f);
  float var = S2 * (1.0f / 768.0f) - mean * mean;
  float rstd = rsqrtf(var + 1e-5f);
  ushort_t* orow = out + (size_t)row * 768;
  orow[tid]       = f2bf((v0 - mean) * rstd * g[tid]       + b[tid]);
  orow[tid + 256] = f2bf((v1 - mean) * rstd * g[tid + 256] + b[tid + 256]);
  orow[tid + 512] = f2bf((v2 - mean) * rstd * g[tid + 512] + b[tid + 512]);
}

// ---------------- pipelined MFMA GEMM ----------------
// C[M,N] = A[M,K] x Bt[N,K]^T, bf16, fp32 accum. BK=64, 256 thr = 4 waves (2x2).
// Register double-buffer: tile k+1 global->VGPR issued right after the staging
// barrier, consumed by next iteration's ds_write (vmcnt drain hidden by compute).
// LDS [row][chunk]: 8 x 16B chunks/row, slot c holds global chunk c^(row&7)
// -> conflict-free b128 reads AND writes, zero padding (verified R4: conflicts=0).
// MINW = min waves/EU (= blocks/CU at 256 thr): pins VGPR budget (512/MINW).
enum { EPI_QKV = 0, EPI_RES = 1, EPI_FC = 2 };

template <int BM, int BN, int EPI, int MINW>
__global__ void __launch_bounds__(256, MINW) gemm_p(
    const ushort_t* __restrict__ A, const ushort_t* __restrict__ Bt,
    int M, int N, int K,
    const float* __restrict__ b0, const float* __restrict__ b1, const float* __restrict__ b2,
    const float* __restrict__ resid,
    ushort_t* __restrict__ ob0, ushort_t* __restrict__ ob1, ushort_t* __restrict__ ob2,
    float* __restrict__ of) {
  constexpr int WM = BM / 2, WN = BN / 2;
  constexpr int NI = WM / 16, NJ = WN / 16;
  constexpr int AL = (BM * 64) / (256 * 8);   // uint4 loads per thread (A)
  constexpr int BL = (BN * 64) / (256 * 8);   // uint4 loads per thread (B)
  __shared__ __align__(16) ushort_t la[BM * 64];
  __shared__ __align__(16) ushort_t lb[BN * 64];
  int tid = threadIdx.x;
  int lane = tid & 63;
  int w = tid >> 6;
  int wr = w >> 1, wc = w & 1;
  int lm = lane & 15, q = lane >> 4;
  int m0 = blockIdx.x * BM, n0 = blockIdx.y * BN;

  const ushort_t* Ab = A + (size_t)m0 * K;
  const ushort_t* Bb = Bt + (size_t)n0 * K;

  floatx4 acc[NI][NJ];
  #pragma unroll
  for (int i = 0; i < NI; ++i)
    #pragma unroll
    for (int j = 0; j < NJ; ++j) acc[i][j] = (floatx4){0.f, 0.f, 0.f, 0.f};

  uint4 ar[AL], br[BL];
  // prologue: tile 0 -> regs
  #pragma unroll
  for (int i = 0; i < AL; ++i) {
    int idx = tid + i * 256, row = idx >> 3, ch = idx & 7;
    ar[i] = *reinterpret_cast<const uint4*>(Ab + (size_t)row * K + ch * 8);
  }
  #pragma unroll
  for (int i = 0; i < BL; ++i) {
    int idx = tid + i * 256, row = idx >> 3, ch = idx & 7;
    br[i] = *reinterpret_cast<const uint4*>(Bb + (size_t)row * K + ch * 8);
  }

  for (int k0 = 0; k0 < K; k0 += 64) {
    __syncthreads();   // all waves done reading la/lb of previous tile
    #pragma unroll
    for (int i = 0; i < AL; ++i) {
      int idx = tid + i * 256, row = idx >> 3, ch = idx & 7;
      *reinterpret_cast<uint4*>(&la[row * 64 + ((ch ^ (row & 7)) << 3)]) = ar[i];
    }
    #pragma unroll
    for (int i = 0; i < BL; ++i) {
      int idx = tid + i * 256, row = idx >> 3, ch = idx & 7;
      *reinterpret_cast<uint4*>(&lb[row * 64 + ((ch ^ (row & 7)) << 3)]) = br[i];
    }
    __syncthreads();
    // prefetch tile k+1 (consumed next iteration; latency hidden by MFMAs below)
    if (k0 + 64 < K) {
      #pragma unroll
      for (int i = 0; i < AL; ++i) {
        int idx = tid + i * 256, row = idx >> 3, ch = idx & 7;
        ar[i] = *reinterpret_cast<const uint4*>(Ab + (size_t)row * K + k0 + 64 + ch * 8);
      }
      #pragma unroll
      for (int i = 0; i < BL; ++i) {
        int idx = tid + i * 256, row = idx >> 3, ch = idx & 7;
        br[i] = *reinterpret_cast<const uint4*>(Bb + (size_t)row * K + k0 + 64 + ch * 8);
      }
    }
    #pragma unroll
    for (int kk = 0; kk < 64; kk += 32) {
      bf16x8 af[NI], bfr[NJ];
      #pragma unroll
      for (int i = 0; i < NI; ++i) {
        int ra = wr * WM + i * 16 + lm;
        int ch = (kk >> 3) + q;
        af[i] = *reinterpret_cast<const bf16x8*>(&la[ra * 64 + ((ch ^ (ra & 7)) << 3)]);
      }
      #pragma unroll
      for (int j = 0; j < NJ; ++j) {
        int rb = wc * WN + j * 16 + lm;
        int ch = (kk >> 3) + q;
        bfr[j] = *reinterpret_cast<const bf16x8*>(&lb[rb * 64 + ((ch ^ (rb & 7)) << 3)]);
      }
      #pragma unroll
      for (int i = 0; i < NI; ++i)
        #pragma unroll
        for (int j = 0; j < NJ; ++j)
          acc[i][j] = __builtin_amdgcn_mfma_f32_16x16x32_bf16(af[i], bfr[j], acc[i][j], 0, 0, 0);
    }
  }

  // epilogue; C/D layout: row(m)=quad*4+reg, col(n)=lane&15  [verified m89/m91]
  #pragma unroll
  for (int i = 0; i < NI; ++i) {
    #pragma unroll
    for (int j = 0; j < NJ; ++j) {
      #pragma unroll
      for (int r = 0; r < 4; ++r) {
        float vacc = acc[i][j][r];
        int mm = m0 + wr * WM + i * 16 + q * 4 + r;
        int nn = n0 + wc * WN + j * 16 + lm;
        if constexpr (EPI == EPI_QKV) {
          int sel = nn / 768;            // 0:q 1:k 2:v
          int nq = nn - sel * 768;       // h*64+hd
          const float* bp = (sel == 0) ? b0 : (sel == 1) ? b1 : b2;
          ushort_t* dst = (sel == 0) ? ob0 : (sel == 1) ? ob1 : ob2;
          int bh = (mm >> 10) * 12 + (nq >> 6);
          size_t o = (size_t)bh * 65536 + (size_t)(mm & 1023) * 64 + (nq & 63);
          dst[o] = f2bf(vacc + bp[nq]);
        } else if constexpr (EPI == EPI_RES) {
          size_t o = (size_t)mm * 768 + nn;
          of[o] = vacc + b0[nn] + resid[o];
        } else {  // EPI_FC: gelu(acc+bias) -> bf16 [M,3072]
          float u = vacc + b0[nn];
          float inner = 0.7978845608028654f * (u + 0.044715f * u * u * u);
          float gl = 0.5f * u * (1.0f + tanhf(inner));
          ob0[(size_t)mm * 3072 + nn] = f2bf(gl);
        }
      }
    }
  }
}

// ---------------- V transpose: [bh][1024][64] -> [bh][64][1024] (bf16) ----------------
__global__ void __launch_bounds__(256) transpose_v(const ushort_t* __restrict__ vb,
                                                   ushort_t* __restrict__ vt) {
  __shared__ ushort_t tl[64 * 72];
  int kt = blockIdx.x, bh = blockIdx.y;
  size_t base = (size_t)bh * 65536;
  int tid = threadIdx.x;
  #pragma unroll
  for (int i = 0; i < 2; ++i) {
    int r = (tid >> 3) + i * 32;     // local key row
    int cb = (tid & 7) * 8;          // dim chunk
    *reinterpret_cast<uint4*>(&tl[r * 72 + cb]) =
        *reinterpret_cast<const uint4*>(vb + base + (size_t)(kt * 64 + r) * 64 + cb);
  }
  __syncthreads();
  #pragma unroll
  for (int i = 0; i < 2; ++i) {
    int dim = (tid >> 3) + i * 32;
    int kb8 = (tid & 7) * 8;
    ushort_t tmp[8];
    #pragma unroll
    for (int j = 0; j < 8; ++j) tmp[j] = tl[(kb8 + j) * 72 + dim];
    *reinterpret_cast<uint4*>(vt + base + (size_t)dim * 1024 + kt * 64 + kb8) =
        *reinterpret_cast<uint4*>(tmp);
  }
}

// ---------------- MFMA flash attention ----------------
// grid (16, 96): x = reversed q-tile (64 queries), y = bh. 4 waves x 16 queries.
__global__ void __launch_bounds__(256) attn_mfma(const ushort_t* __restrict__ qb,
                                                 const ushort_t* __restrict__ kb,
                                                 const ushort_t* __restrict__ vtb,
                                                 ushort_t* __restrict__ yb) {
  __shared__ __align__(16) ushort_t kl[64 * 72];   // K tile [key][dim]
  __shared__ __align__(16) ushort_t vtl[64 * 72];  // V^T tile [dim][key]
  int qt = (int)gridDim.x - 1 - (int)blockIdx.x;   // big tiles dispatch first
  int bh = blockIdx.y;
  int tid = threadIdx.x, lane = tid & 63, w = tid >> 6;
  int col = lane & 15, quad = lane >> 4;
  int qw0 = qt * 64 + w * 16;                      // wave's first query
  size_t base = (size_t)bh * 65536;

  bf16x8 qf0 = *reinterpret_cast<const bf16x8*>(qb + base + (size_t)(qw0 + col) * 64 + quad * 8);
  bf16x8 qf1 = *reinterpret_cast<const bf16x8*>(qb + base + (size_t)(qw0 + col) * 64 + 32 + quad * 8);

  floatx4 O[4];
  #pragma unroll
  for (int s = 0; s < 4; ++s) O[s] = (floatx4){0.f, 0.f, 0.f, 0.f};
  float m = -INFINITY, l = 0.f;
  const float sscale = 0.125f * 1.4426950408889634f;  // 1/sqrt(64) * log2(e)

  for (int kt0 = 0; kt0 <= qt * 64; kt0 += 64) {
    __syncthreads();
    #pragma unroll
    for (int i = 0; i < 2; ++i) {
      int r = (tid >> 3) + i * 32;
      int cb = (tid & 7) * 8;
      *reinterpret_cast<uint4*>(&kl[r * 72 + cb]) =
          *reinterpret_cast<const uint4*>(kb + base + (size_t)(kt0 + r) * 64 + cb);
      *reinterpret_cast<uint4*>(&vtl[r * 72 + cb]) =
          *reinterpret_cast<const uint4*>(vtb + base + (size_t)r * 1024 + kt0 + cb);
    }
    __syncthreads();
    int nsub = ((qw0 + 15 - kt0) >> 4) + 1;
    if (nsub > 4) nsub = 4;
    for (int sub = 0; sub < nsub; ++sub) {
      int ks = kt0 + sub * 16;
      bf16x8 kf0 = *reinterpret_cast<const bf16x8*>(&kl[(sub * 16 + col) * 72 + quad * 8]);
      bf16x8 kf1 = *reinterpret_cast<const bf16x8*>(&kl[(sub * 16 + col) * 72 + 32 + quad * 8]);
      floatx4 sa = (floatx4){0.f, 0.f, 0.f, 0.f};
      sa = __builtin_amdgcn_mfma_f32_16x16x32_bf16(kf0, qf0, sa, 0, 0, 0);
      sa = __builtin_amdgcn_mfma_f32_16x16x32_bf16(kf1, qf1, sa, 0, 0, 0);
      float s0 = sa[0] * sscale, s1 = sa[1] * sscale;
      float s2 = sa[2] * sscale, s3 = sa[3] * sscale;
      if (ks + 15 > qw0) {  // wave-uniform: subtile touches the diagonal
        int keyb = ks + quad * 4;
        int qg = qw0 + col;
        if (keyb + 0 > qg) s0 = -3.0e38f;
        if (keyb + 1 > qg) s1 = -3.0e38f;
        if (keyb + 2 > qg) s2 = -3.0e38f;
        if (keyb + 3 > qg) s3 = -3.0e38f;
      }
      float mloc = fmaxf(fmaxf(s0, s1), fmaxf(s2, s3));
      mloc = fmaxf(mloc, __shfl_xor(mloc, 16, 64));
      mloc = fmaxf(mloc, __shfl_xor(mloc, 32, 64));
      float mnew = fmaxf(m, mloc);
      float c = __builtin_amdgcn_exp2f(m - mnew);
      float p0 = __builtin_amdgcn_exp2f(s0 - mnew);
      float p1 = __builtin_amdgcn_exp2f(s1 - mnew);
      float p2 = __builtin_amdgcn_exp2f(s2 - mnew);
      float p3 = __builtin_amdgcn_exp2f(s3 - mnew);
      float ll = (p0 + p1) + (p2 + p3);
      ll += __shfl_xor(ll, 16, 64);
      ll += __shfl_xor(ll, 32, 64);
      l = l * c + ll;
      m = mnew;
      float c0 = __shfl(c, quad * 4 + 0, 64);
      float c1 = __shfl(c, quad * 4 + 1, 64);
      float c2 = __shfl(c, quad * 4 + 2, 64);
      float c3 = __shfl(c, quad * 4 + 3, 64);
      bf16x8 pf = {(__bf16)p0, (__bf16)p1, (__bf16)p2, (__bf16)p3,
                   (__bf16)0.f, (__bf16)0.f, (__bf16)0.f, (__bf16)0.f};
      #pragma unroll
      for (int s = 0; s < 4; ++s) {
        O[s][0] *= c0; O[s][1] *= c1; O[s][2] *= c2; O[s][3] *= c3;
        bf16x4 v4 = *reinterpret_cast<const bf16x4*>(
            &vtl[(s * 16 + col) * 72 + sub * 16 + quad * 4]);
        bf16x8 vf = {v4[0], v4[1], v4[2], v4[3],
                     (__bf16)0.f, (__bf16)0.f, (__bf16)0.f, (__bf16)0.f};
        O[s] = __builtin_amdgcn_mfma_f32_16x16x32_bf16(pf, vf, O[s], 0, 0, 0);
      }
    }
  }
  float linv = 1.0f / l;
  float l0 = __shfl(linv, quad * 4 + 0, 64);
  float l1 = __shfl(linv, quad * 4 + 1, 64);
  float l2 = __shfl(linv, quad * 4 + 2, 64);
  float l3 = __shfl(linv, quad * 4 + 3, 64);
  int b = bh / 12, h = bh - b * 12;
  #pragma unroll
  for (int s = 0; s < 4; ++s) {
    float lr[4] = {l0, l1, l2, l3};
    #pragma unroll
    for (int r = 0; r < 4; ++r) {
      int t = qw0 + quad * 4 + r;
      yb[((size_t)(b * 1024 + t)) * 768 + h * 64 + s * 16 + col] = f2bf(O[s][r] * lr[r]);
    }
  }
}

// ---------------- launch ----------------
extern "C" void kernel_launch(void* const* d_in, const int* in_sizes, int n_in,
                              void* d_out, int out_size, void* d_ws, size_t ws_size,
                              hipStream_t stream) {
  const float* x      = (const float*)d_in[0];
  const float* wq     = (const float*)d_in[1];
  const float* bq     = (const float*)d_in[2];
  const float* wk     = (const float*)d_in[3];
  const float* bk     = (const float*)d_in[4];
  const float* wv     = (const float*)d_in[5];
  const float* bv     = (const float*)d_in[6];
  const float* w_proj = (const float*)d_in[7];
  const float* b_proj = (const float*)d_in[8];
  const float* g1     = (const float*)d_in[9];
  const float* be1    = (const float*)d_in[10];
  const float* g2     = (const float*)d_in[11];
  const float* be2    = (const float*)d_in[12];
  const float* w_fc   = (const float*)d_in[13];
  const float* b_fc   = (const float*)d_in[14];
  const float* w_cp   = (const float*)d_in[15];
  const float* b_cp   = (const float*)d_in[16];
  float* out = (float*)d_out;

  char* ws = (char*)d_ws;
  size_t off = 0;
  auto alloc = [&](size_t bytes) -> char* {
    char* p = ws + off;
    off += (bytes + 255) & ~(size_t)255;
    return p;
  };
  const size_t MD = 8192ull * 768;  // B*T*D elements
  ushort_t* wqkvT  = (ushort_t*)alloc(2304ull * 768 * 2);   // [N=2304][K=768]
  ushort_t* wprojT = (ushort_t*)alloc(768ull * 768 * 2);    // [N=768][K=768]
  ushort_t* wfcT   = (ushort_t*)alloc(3072ull * 768 * 2);   // [N=3072][K=768]
  ushort_t* wcpT   = (ushort_t*)alloc(768ull * 3072 * 2);   // [N=768][K=3072]
  ushort_t* hbuf   = (ushort_t*)alloc(MD * 2);
  ushort_t* qbuf   = (ushort_t*)alloc(MD * 2);
  ushort_t* kbuf   = (ushort_t*)alloc(MD * 2);
  ushort_t* vbuf   = (ushort_t*)alloc(MD * 2);
  ushort_t* ybuf   = (ushort_t*)alloc(MD * 2);
  float*    x1     = (float*)alloc(MD * 4);
  ushort_t* h2buf  = (ushort_t*)alloc(MD * 2);
  // aliases (lifetimes disjoint): vtbuf reuses hbuf (dead after QKV GEMM);
  // fcbuf reuses qbuf..ybuf (48 MB exactly, dead after proj GEMM)
  ushort_t* vtbuf  = hbuf;
  ushort_t* fcbuf  = qbuf;

  // weight repack: fp32 -> bf16 transposed [N][K]
  repack_qkv_t<<<dim3(12, 36), 256, 0, stream>>>(wq, wk, wv, wqkvT);
  transpose_w<<<dim3(12, 12), 256, 0, stream>>>(w_proj, wprojT, 768, 768);
  transpose_w<<<dim3(48, 12), 256, 0, stream>>>(w_fc, wfcT, 768, 3072);
  transpose_w<<<dim3(12, 48), 256, 0, stream>>>(w_cp, wcpT, 3072, 768);

  // LN1
  ln_kernel<<<8192, 256, 0, stream>>>(x, g1, be1, hbuf);
  // QKV projection (fused q|k|v, scatter to [B,H,T,HD] bf16)
  gemm_p<128, 128, EPI_QKV, 2><<<dim3(64, 18), 256, 0, stream>>>(
      hbuf, wqkvT, 8192, 2304, 768, bq, bk, bv, nullptr, qbuf, kbuf, vbuf, nullptr);
  // V -> V^T  (hbuf dead, reused as vtbuf)
  transpose_v<<<dim3(16, 96), 256, 0, stream>>>(vbuf, vtbuf);
  // causal MFMA flash attention
  attn_mfma<<<dim3(16, 96), 256, 0, stream>>>(qbuf, kbuf, vtbuf, ybuf);
  // out-proj + bias + residual(x) -> x1 fp32 (64x128 tile: 768 blocks, 3/CU)
  gemm_p<64, 128, EPI_RES, 3><<<dim3(128, 6), 256, 0, stream>>>(
      ybuf, wprojT, 8192, 768, 768, b_proj, nullptr, nullptr, x,
      nullptr, nullptr, nullptr, x1);
  // LN2
  ln_kernel<<<8192, 256, 0, stream>>>(x1, g2, be2, h2buf);
  // FC + gelu -> bf16 (fcbuf aliases qbuf..ybuf, all dead now)
  gemm_p<128, 128, EPI_FC, 2><<<dim3(64, 24), 256, 0, stream>>>(
      h2buf, wfcT, 8192, 3072, 768, b_fc, nullptr, nullptr, nullptr,
      fcbuf, nullptr, nullptr, nullptr);
  // CP + bias + residual(x1) -> out fp32 (64x128 tile: 768 blocks, 3/CU)
  gemm_p<64, 128, EPI_RES, 3><<<dim3(128, 6), 256, 0, stream>>>(
      fcbuf, wcpT, 8192, 768, 3072, b_cp, nullptr, nullptr, x1,
      nullptr, nullptr, nullptr, out);
}

// Round 10
// 446.946 us; speedup vs baseline: 2.0518x; 2.0518x over previous
//
#include <hip/hip_runtime.h>
#include <math.h>

// DecoderBlock: B=8, T=1024, D=768, H=12, HD=64
// x fp32 [B,T,D]; per-head wq/wk/wv [H,D,HD]; w_proj [D,D]; w_fc [D,4D]; w_cp [4D,D]
// out fp32 [B,T,D]
//
// Lessons encoded here:
//  R3: global_load_lds serves stale data when source was written by a prior
//      kernel (warm-launch divergence) -> VGPR staging only.
//  R7/R9: register double-buffer prefetch triggers pathological scratch spill
//      (WRITE_SIZE 689-750 MB, VGPR forced to 44-64); __launch_bounds__ minw
//      does NOT prevent it. -> no prefetch; rely on TLP (R2: 8 blocks/CU hid
//      all latency).
//  R4: XOR-swizzled [row][chunk^row&7] LDS layout gives 0 bank conflicts for
//      b128 writes AND reads. R2's conflict cost was 62 us/dispatch.

typedef unsigned short ushort_t;
typedef __attribute__((ext_vector_type(8))) __bf16 bf16x8;
typedef __attribute__((ext_vector_type(4))) __bf16 bf16x4;
typedef __attribute__((ext_vector_type(4))) float floatx4;

__device__ __forceinline__ float bf2f(ushort_t u) {
  unsigned int x = ((unsigned int)u) << 16;
  return __builtin_bit_cast(float, x);
}
__device__ __forceinline__ ushort_t f2bf(float f) {
  unsigned int x = __builtin_bit_cast(unsigned int, f);
  unsigned int r = (x + 0x7FFFu + ((x >> 16) & 1u)) >> 16;
  return (ushort_t)r;
}

// ---------------- weight repack: fp32 [R][C] -> bf16 [C][R] (tiled, coalesced) ----------
__global__ void __launch_bounds__(256) transpose_w(const float* __restrict__ in,
                                                   ushort_t* __restrict__ out,
                                                   int R, int C) {
  __shared__ ushort_t tl[64][65];
  int c0 = blockIdx.x * 64, r0 = blockIdx.y * 64;
  #pragma unroll
  for (int i = 0; i < 16; ++i) {
    int idx = threadIdx.x + i * 256;
    int r = idx >> 6, c = idx & 63;
    tl[c][r] = f2bf(in[(size_t)(r0 + r) * C + c0 + c]);
  }
  __syncthreads();
  #pragma unroll
  for (int i = 0; i < 16; ++i) {
    int idx = threadIdx.x + i * 256;
    int c = idx >> 6, r = idx & 63;
    out[(size_t)(c0 + c) * R + r0 + r] = tl[c][r];
  }
}

// wq/wk/wv [H,D,HD] fp32 -> wqkvT [N=2304][K=768] bf16 (N = s*768 + h*64 + hd)
__global__ void __launch_bounds__(256) repack_qkv_t(const float* __restrict__ wq,
                                                    const float* __restrict__ wk,
                                                    const float* __restrict__ wv,
                                                    ushort_t* __restrict__ out) {
  __shared__ ushort_t tl[64][65];
  int s = blockIdx.y / 12, h = blockIdx.y % 12;
  const float* w = ((s == 0) ? wq : (s == 1) ? wk : wv) + (size_t)h * 768 * 64;
  int d0 = blockIdx.x * 64;
  #pragma unroll
  for (int i = 0; i < 16; ++i) {
    int idx = threadIdx.x + i * 256;
    int r = idx >> 6, c = idx & 63;   // r: d offset, c: hd
    tl[c][r] = f2bf(w[(size_t)(d0 + r) * 64 + c]);
  }
  __syncthreads();
  ushort_t* ob = out + (size_t)(s * 768 + h * 64) * 768;
  #pragma unroll
  for (int i = 0; i < 16; ++i) {
    int idx = threadIdx.x + i * 256;
    int c = idx >> 6, r = idx & 63;   // c: hd, r: d offset
    ob[(size_t)c * 768 + d0 + r] = tl[c][r];
  }
}

// ---------------- layernorm: fp32 row [768] -> bf16 row ----------------
__global__ void __launch_bounds__(256) ln_kernel(const float* __restrict__ x,
                                                 const float* __restrict__ g,
                                                 const float* __restrict__ b,
                                                 ushort_t* __restrict__ out) {
  int row = blockIdx.x;
  int tid = threadIdx.x;
  const float* xr = x + (size_t)row * 768;
  float v0 = xr[tid], v1 = xr[tid + 256], v2 = xr[tid + 512];
  float s = v0 + v1 + v2;
  float s2 = v0 * v0 + v1 * v1 + v2 * v2;
  #pragma unroll
  for (int off = 32; off; off >>= 1) {
    s += __shfl_xor(s, off, 64);
    s2 += __shfl_xor(s2, off, 64);
  }
  __shared__ float ws1[4], ws2[4];
  int w = tid >> 6;
  if ((tid & 63) == 0) { ws1[w] = s; ws2[w] = s2; }
  __syncthreads();
  float S = ws1[0] + ws1[1] + ws1[2] + ws1[3];
  float S2 = ws2[0] + ws2[1] + ws2[2] + ws2[3];
  float mean = S * (1.0f / 768.0f);
  float var = S2 * (1.0f / 768.0f) - mean * mean;
  float rstd = rsqrtf(var + 1e-5f);
  ushort_t* orow = out + (size_t)row * 768;
  orow[tid]       = f2bf((v0 - mean) * rstd * g[tid]       + b[tid]);
  orow[tid + 256] = f2bf((v1 - mean) * rstd * g[tid + 256] + b[tid + 256]);
  orow[tid + 512] = f2bf((v2 - mean) * rstd * g[tid + 512] + b[tid + 512]);
}

// ---------------- 64x64 MFMA GEMM (high-TLP, conflict-free staging) ----------------
// C[M,N] = A[M,K] x Bt[N,K]^T, bf16, fp32 accum. BK=64, 256 thr = 4 waves (2x2),
// wave = 32x32 = 2x2 MFMA 16x16x32. LDS 16 KB, VGPR ~60 -> ~6 blocks/CU: TLP
// hides global-load latency (R2-proven). LDS [row][chunk]: 8x16B chunks/row,
// slot c holds global chunk c^(row&7) -> 0 bank conflicts (R4-verified).
enum { EPI_QKV = 0, EPI_RES = 1, EPI_FC = 2 };

template <int EPI>
__global__ void __launch_bounds__(256) gemm64(
    const ushort_t* __restrict__ A, const ushort_t* __restrict__ Bt,
    int M, int N, int K,
    const float* __restrict__ b0, const float* __restrict__ b1, const float* __restrict__ b2,
    const float* __restrict__ resid,
    ushort_t* __restrict__ ob0, ushort_t* __restrict__ ob1, ushort_t* __restrict__ ob2,
    float* __restrict__ of) {
  __shared__ __align__(16) ushort_t la[64 * 64];
  __shared__ __align__(16) ushort_t lb[64 * 64];
  int tid = threadIdx.x;
  int lane = tid & 63;
  int w = tid >> 6;
  int wr = w >> 1, wc = w & 1;
  int lm = lane & 15, q = lane >> 4;
  int m0 = blockIdx.x * 64, n0 = blockIdx.y * 64;

  const ushort_t* Ab = A + (size_t)m0 * K;
  const ushort_t* Bb = Bt + (size_t)n0 * K;

  floatx4 acc[2][2];
  #pragma unroll
  for (int i = 0; i < 2; ++i)
    #pragma unroll
    for (int j = 0; j < 2; ++j) acc[i][j] = (floatx4){0.f, 0.f, 0.f, 0.f};

  // per-thread staging coords: 2 uint4 per matrix per K-tile
  int srow0 = tid >> 3;           // 0..31
  int sch   = tid & 7;            // chunk 0..7
  for (int k0 = 0; k0 < K; k0 += 64) {
    uint4 av0 = *reinterpret_cast<const uint4*>(Ab + (size_t)srow0 * K + k0 + sch * 8);
    uint4 av1 = *reinterpret_cast<const uint4*>(Ab + (size_t)(srow0 + 32) * K + k0 + sch * 8);
    uint4 bv0 = *reinterpret_cast<const uint4*>(Bb + (size_t)srow0 * K + k0 + sch * 8);
    uint4 bv1 = *reinterpret_cast<const uint4*>(Bb + (size_t)(srow0 + 32) * K + k0 + sch * 8);
    __syncthreads();   // previous tile's LDS reads all consumed
    *reinterpret_cast<uint4*>(&la[srow0 * 64 + ((sch ^ (srow0 & 7)) << 3)]) = av0;
    *reinterpret_cast<uint4*>(&la[(srow0 + 32) * 64 + ((sch ^ (srow0 & 7)) << 3)]) = av1;
    *reinterpret_cast<uint4*>(&lb[srow0 * 64 + ((sch ^ (srow0 & 7)) << 3)]) = bv0;
    *reinterpret_cast<uint4*>(&lb[(srow0 + 32) * 64 + ((sch ^ (srow0 & 7)) << 3)]) = bv1;
    __syncthreads();
    #pragma unroll
    for (int kk = 0; kk < 64; kk += 32) {
      int ch = (kk >> 3) + q;
      bf16x8 af[2], bfr[2];
      #pragma unroll
      for (int i = 0; i < 2; ++i) {
        int ra = wr * 32 + i * 16 + lm;
        int rb = wc * 32 + i * 16 + lm;
        af[i]  = *reinterpret_cast<const bf16x8*>(&la[ra * 64 + ((ch ^ (ra & 7)) << 3)]);
        bfr[i] = *reinterpret_cast<const bf16x8*>(&lb[rb * 64 + ((ch ^ (rb & 7)) << 3)]);
      }
      #pragma unroll
      for (int i = 0; i < 2; ++i)
        #pragma unroll
        for (int j = 0; j < 2; ++j)
          acc[i][j] = __builtin_amdgcn_mfma_f32_16x16x32_bf16(af[i], bfr[j], acc[i][j], 0, 0, 0);
    }
  }

  // epilogue; C/D layout: row(m)=quad*4+reg, col(n)=lane&15  [verified m89/m91]
  #pragma unroll
  for (int i = 0; i < 2; ++i) {
    #pragma unroll
    for (int j = 0; j < 2; ++j) {
      #pragma unroll
      for (int r = 0; r < 4; ++r) {
        float vacc = acc[i][j][r];
        int mm = m0 + wr * 32 + i * 16 + q * 4 + r;
        int nn = n0 + wc * 32 + j * 16 + lm;
        if constexpr (EPI == EPI_QKV) {
          int sel = nn / 768;            // 0:q 1:k 2:v (uniform: 64 | 768)
          int nq = nn - sel * 768;       // h*64+hd
          const float* bp = (sel == 0) ? b0 : (sel == 1) ? b1 : b2;
          ushort_t* dst = (sel == 0) ? ob0 : (sel == 1) ? ob1 : ob2;
          int bh = (mm >> 10) * 12 + (nq >> 6);
          size_t o = (size_t)bh * 65536 + (size_t)(mm & 1023) * 64 + (nq & 63);
          dst[o] = f2bf(vacc + bp[nq]);
        } else if constexpr (EPI == EPI_RES) {
          size_t o = (size_t)mm * 768 + nn;
          of[o] = vacc + b0[nn] + resid[o];
        } else {  // EPI_FC: gelu(acc+bias) -> bf16 [M,3072]
          float u = vacc + b0[nn];
          float inner = 0.7978845608028654f * (u + 0.044715f * u * u * u);
          float gl = 0.5f * u * (1.0f + tanhf(inner));
          ob0[(size_t)mm * 3072 + nn] = f2bf(gl);
        }
      }
    }
  }
}

// ---------------- V transpose: [bh][1024][64] -> [bh][64][1024] (bf16) ----------------
__global__ void __launch_bounds__(256) transpose_v(const ushort_t* __restrict__ vb,
                                                   ushort_t* __restrict__ vt) {
  __shared__ ushort_t tl[64 * 72];
  int kt = blockIdx.x, bh = blockIdx.y;
  size_t base = (size_t)bh * 65536;
  int tid = threadIdx.x;
  #pragma unroll
  for (int i = 0; i < 2; ++i) {
    int r = (tid >> 3) + i * 32;     // local key row
    int cb = (tid & 7) * 8;          // dim chunk
    *reinterpret_cast<uint4*>(&tl[r * 72 + cb]) =
        *reinterpret_cast<const uint4*>(vb + base + (size_t)(kt * 64 + r) * 64 + cb);
  }
  __syncthreads();
  #pragma unroll
  for (int i = 0; i < 2; ++i) {
    int dim = (tid >> 3) + i * 32;
    int kb8 = (tid & 7) * 8;
    ushort_t tmp[8];
    #pragma unroll
    for (int j = 0; j < 8; ++j) tmp[j] = tl[(kb8 + j) * 72 + dim];
    *reinterpret_cast<uint4*>(vt + base + (size_t)dim * 1024 + kt * 64 + kb8) =
        *reinterpret_cast<uint4*>(tmp);
  }
}

// ---------------- MFMA flash attention ----------------
// grid (16, 96): x = reversed q-tile (64 queries), y = bh. 4 waves x 16 queries.
__global__ void __launch_bounds__(256) attn_mfma(const ushort_t* __restrict__ qb,
                                                 const ushort_t* __restrict__ kb,
                                                 const ushort_t* __restrict__ vtb,
                                                 ushort_t* __restrict__ yb) {
  __shared__ __align__(16) ushort_t kl[64 * 72];   // K tile [key][dim]
  __shared__ __align__(16) ushort_t vtl[64 * 72];  // V^T tile [dim][key]
  int qt = (int)gridDim.x - 1 - (int)blockIdx.x;   // big tiles dispatch first
  int bh = blockIdx.y;
  int tid = threadIdx.x, lane = tid & 63, w = tid >> 6;
  int col = lane & 15, quad = lane >> 4;
  int qw0 = qt * 64 + w * 16;                      // wave's first query
  size_t base = (size_t)bh * 65536;

  bf16x8 qf0 = *reinterpret_cast<const bf16x8*>(qb + base + (size_t)(qw0 + col) * 64 + quad * 8);
  bf16x8 qf1 = *reinterpret_cast<const bf16x8*>(qb + base + (size_t)(qw0 + col) * 64 + 32 + quad * 8);

  floatx4 O[4];
  #pragma unroll
  for (int s = 0; s < 4; ++s) O[s] = (floatx4){0.f, 0.f, 0.f, 0.f};
  float m = -INFINITY, l = 0.f;
  const float sscale = 0.125f * 1.4426950408889634f;  // 1/sqrt(64) * log2(e)

  for (int kt0 = 0; kt0 <= qt * 64; kt0 += 64) {
    __syncthreads();
    #pragma unroll
    for (int i = 0; i < 2; ++i) {
      int r = (tid >> 3) + i * 32;
      int cb = (tid & 7) * 8;
      *reinterpret_cast<uint4*>(&kl[r * 72 + cb]) =
          *reinterpret_cast<const uint4*>(kb + base + (size_t)(kt0 + r) * 64 + cb);
      *reinterpret_cast<uint4*>(&vtl[r * 72 + cb]) =
          *reinterpret_cast<const uint4*>(vtb + base + (size_t)r * 1024 + kt0 + cb);
    }
    __syncthreads();
    int nsub = ((qw0 + 15 - kt0) >> 4) + 1;
    if (nsub > 4) nsub = 4;
    for (int sub = 0; sub < nsub; ++sub) {
      int ks = kt0 + sub * 16;
      bf16x8 kf0 = *reinterpret_cast<const bf16x8*>(&kl[(sub * 16 + col) * 72 + quad * 8]);
      bf16x8 kf1 = *reinterpret_cast<const bf16x8*>(&kl[(sub * 16 + col) * 72 + 32 + quad * 8]);
      floatx4 sa = (floatx4){0.f, 0.f, 0.f, 0.f};
      sa = __builtin_amdgcn_mfma_f32_16x16x32_bf16(kf0, qf0, sa, 0, 0, 0);
      sa = __builtin_amdgcn_mfma_f32_16x16x32_bf16(kf1, qf1, sa, 0, 0, 0);
      float s0 = sa[0] * sscale, s1 = sa[1] * sscale;
      float s2 = sa[2] * sscale, s3 = sa[3] * sscale;
      if (ks + 15 > qw0) {  // wave-uniform: subtile touches the diagonal
        int keyb = ks + quad * 4;
        int qg = qw0 + col;
        if (keyb + 0 > qg) s0 = -3.0e38f;
        if (keyb + 1 > qg) s1 = -3.0e38f;
        if (keyb + 2 > qg) s2 = -3.0e38f;
        if (keyb + 3 > qg) s3 = -3.0e38f;
      }
      float mloc = fmaxf(fmaxf(s0, s1), fmaxf(s2, s3));
      mloc = fmaxf(mloc, __shfl_xor(mloc, 16, 64));
      mloc = fmaxf(mloc, __shfl_xor(mloc, 32, 64));
      float mnew = fmaxf(m, mloc);
      float c = __builtin_amdgcn_exp2f(m - mnew);
      float p0 = __builtin_amdgcn_exp2f(s0 - mnew);
      float p1 = __builtin_amdgcn_exp2f(s1 - mnew);
      float p2 = __builtin_amdgcn_exp2f(s2 - mnew);
      float p3 = __builtin_amdgcn_exp2f(s3 - mnew);
      float ll = (p0 + p1) + (p2 + p3);
      ll += __shfl_xor(ll, 16, 64);
      ll += __shfl_xor(ll, 32, 64);
      l = l * c + ll;
      m = mnew;
      float c0 = __shfl(c, quad * 4 + 0, 64);
      float c1 = __shfl(c, quad * 4 + 1, 64);
      float c2 = __shfl(c, quad * 4 + 2, 64);
      float c3 = __shfl(c, quad * 4 + 3, 64);
      bf16x8 pf = {(__bf16)p0, (__bf16)p1, (__bf16)p2, (__bf16)p3,
                   (__bf16)0.f, (__bf16)0.f, (__bf16)0.f, (__bf16)0.f};
      #pragma unroll
      for (int s = 0; s < 4; ++s) {
        O[s][0] *= c0; O[s][1] *= c1; O[s][2] *= c2; O[s][3] *= c3;
        bf16x4 v4 = *reinterpret_cast<const bf16x4*>(
            &vtl[(s * 16 + col) * 72 + sub * 16 + quad * 4]);
        bf16x8 vf = {v4[0], v4[1], v4[2], v4[3],
                     (__bf16)0.f, (__bf16)0.f, (__bf16)0.f, (__bf16)0.f};
        O[s] = __builtin_amdgcn_mfma_f32_16x16x32_bf16(pf, vf, O[s], 0, 0, 0);
      }
    }
  }
  float linv = 1.0f / l;
  float l0 = __shfl(linv, quad * 4 + 0, 64);
  float l1 = __shfl(linv, quad * 4 + 1, 64);
  float l2 = __shfl(linv, quad * 4 + 2, 64);
  float l3 = __shfl(linv, quad * 4 + 3, 64);
  int b = bh / 12, h = bh - b * 12;
  #pragma unroll
  for (int s = 0; s < 4; ++s) {
    float lr[4] = {l0, l1, l2, l3};
    #pragma unroll
    for (int r = 0; r < 4; ++r) {
      int t = qw0 + quad * 4 + r;
      yb[((size_t)(b * 1024 + t)) * 768 + h * 64 + s * 16 + col] = f2bf(O[s][r] * lr[r]);
    }
  }
}

// ---------------- launch ----------------
extern "C" void kernel_launch(void* const* d_in, const int* in_sizes, int n_in,
                              void* d_out, int out_size, void* d_ws, size_t ws_size,
                              hipStream_t stream) {
  const float* x      = (const float*)d_in[0];
  const float* wq     = (const float*)d_in[1];
  const float* bq     = (const float*)d_in[2];
  const float* wk     = (const float*)d_in[3];
  const float* bk     = (const float*)d_in[4];
  const float* wv     = (const float*)d_in[5];
  const float* bv     = (const float*)d_in[6];
  const float* w_proj = (const float*)d_in[7];
  const float* b_proj = (const float*)d_in[8];
  const float* g1     = (const float*)d_in[9];
  const float* be1    = (const float*)d_in[10];
  const float* g2     = (const float*)d_in[11];
  const float* be2    = (const float*)d_in[12];
  const float* w_fc   = (const float*)d_in[13];
  const float* b_fc   = (const float*)d_in[14];
  const float* w_cp   = (const float*)d_in[15];
  const float* b_cp   = (const float*)d_in[16];
  float* out = (float*)d_out;

  char* ws = (char*)d_ws;
  size_t off = 0;
  auto alloc = [&](size_t bytes) -> char* {
    char* p = ws + off;
    off += (bytes + 255) & ~(size_t)255;
    return p;
  };
  const size_t MD = 8192ull * 768;  // B*T*D elements
  ushort_t* wqkvT  = (ushort_t*)alloc(2304ull * 768 * 2);   // [N=2304][K=768]
  ushort_t* wprojT = (ushort_t*)alloc(768ull * 768 * 2);    // [N=768][K=768]
  ushort_t* wfcT   = (ushort_t*)alloc(3072ull * 768 * 2);   // [N=3072][K=768]
  ushort_t* wcpT   = (ushort_t*)alloc(768ull * 3072 * 2);   // [N=768][K=3072]
  ushort_t* hbuf   = (ushort_t*)alloc(MD * 2);
  ushort_t* qbuf   = (ushort_t*)alloc(MD * 2);
  ushort_t* kbuf   = (ushort_t*)alloc(MD * 2);
  ushort_t* vbuf   = (ushort_t*)alloc(MD * 2);
  ushort_t* ybuf   = (ushort_t*)alloc(MD * 2);
  float*    x1     = (float*)alloc(MD * 4);
  ushort_t* h2buf  = (ushort_t*)alloc(MD * 2);
  // aliases (lifetimes disjoint): vtbuf reuses hbuf (dead after QKV GEMM);
  // fcbuf reuses qbuf..ybuf (48 MB exactly, dead after proj GEMM)
  ushort_t* vtbuf  = hbuf;
  ushort_t* fcbuf  = qbuf;

  // weight repack: fp32 -> bf16 transposed [N][K]
  repack_qkv_t<<<dim3(12, 36), 256, 0, stream>>>(wq, wk, wv, wqkvT);
  transpose_w<<<dim3(12, 12), 256, 0, stream>>>(w_proj, wprojT, 768, 768);
  transpose_w<<<dim3(48, 12), 256, 0, stream>>>(w_fc, wfcT, 768, 3072);
  transpose_w<<<dim3(12, 48), 256, 0, stream>>>(w_cp, wcpT, 3072, 768);

  // LN1
  ln_kernel<<<8192, 256, 0, stream>>>(x, g1, be1, hbuf);
  // QKV projection (fused q|k|v, scatter to [B,H,T,HD] bf16)
  gemm64<EPI_QKV><<<dim3(128, 36), 256, 0, stream>>>(
      hbuf, wqkvT, 8192, 2304, 768, bq, bk, bv, nullptr, qbuf, kbuf, vbuf, nullptr);
  // V -> V^T  (hbuf dead, reused as vtbuf)
  transpose_v<<<dim3(16, 96), 256, 0, stream>>>(vbuf, vtbuf);
  // causal MFMA flash attention
  attn_mfma<<<dim3(16, 96), 256, 0, stream>>>(qbuf, kbuf, vtbuf, ybuf);
  // out-proj + bias + residual(x) -> x1 fp32
  gemm64<EPI_RES><<<dim3(128, 12), 256, 0, stream>>>(
      ybuf, wprojT, 8192, 768, 768, b_proj, nullptr, nullptr, x,
      nullptr, nullptr, nullptr, x1);
  // LN2
  ln_kernel<<<8192, 256, 0, stream>>>(x1, g2, be2, h2buf);
  // FC + gelu -> bf16 (fcbuf aliases qbuf..ybuf, all dead now)
  gemm64<EPI_FC><<<dim3(128, 48), 256, 0, stream>>>(
      h2buf, wfcT, 8192, 3072, 768, b_fc, nullptr, nullptr, nullptr,
      fcbuf, nullptr, nullptr, nullptr);
  // CP + bias + residual(x1) -> out fp32
  gemm64<EPI_RES><<<dim3(128, 12), 256, 0, stream>>>(
      fcbuf, wcpT, 8192, 768, 3072, b_cp, nullptr, nullptr, x1,
      nullptr, nullptr, nullptr, out);
}